// Round 6
// baseline (164.066 us; speedup 1.0000x reference)
//
#include <hip/hip_runtime.h>

// PatchStd: out = sqrt( boxconv7(x^2) - boxconv7(x)^2 ), uniform 7x7 weight w.
// x: [16, 1, 1024, 1024] fp32, zero padding 3 on each side.
//
// Uniform weight => conv = w * windowed sum. Thread owns 4 adjacent output
// cols and an 8-row strip (TPB=256, 2048 blocks — R2's proven config).
// Per input row: 3 aligned float4 loads -> sliding-window horizontal 7-sums
// (x, x^2) -> 7-deep register ring. NEW vs R2: vertical window is a RUNNING
// sum (vh += h_new - h_departing; departing row shares the ring slot being
// overwritten; slot 6 zero-init covers the first iteration). This removes
// R2's 48-op full vertical re-sum and its 12 buffer-copy movs (-40% VALU)
// at +8 floats of state. R4 proved VGPR>80 kills occupancy, so loads stay
// 1-ahead double-buffered and __launch_bounds__ caps the allocator.

#define IMG_W 1024
#define IMG_H 1024
#define SH    8             // output rows per block strip
#define TPB   256           // threads/block; 4 cols/thread -> 1024 cols

__global__ __launch_bounds__(TPB, 7) void patchstd_kernel(
    const float* __restrict__ img, const float* __restrict__ wptr,
    float* __restrict__ out)
{
    const int tx = threadIdx.x;
    const int c0 = tx << 2;                       // first of 4 output cols
    const int y0 = blockIdx.y * SH;               // first output row of strip
    const float* base  = img + (size_t)blockIdx.z * (IMG_W * IMG_H);
    float*       obase = out + (size_t)blockIdx.z * (IMG_W * IMG_H);
    const float w = wptr[0];

    const bool interior = (tx > 0) && (tx < 255); // all 12 cols in-range

    float rh[7][4];     // ring: horizontal 7-sums of x   (per row)
    float rq[7][4];     // ring: horizontal 7-sums of x^2 (per row)
    float vh[4] = {0.f, 0.f, 0.f, 0.f};           // running vertical sums
    float vq[4] = {0.f, 0.f, 0.f, 0.f};
    float b[2][12];                               // alternating raw-row buffers

    // Load 12 raw pixels (cols c0-4 .. c0+7) of input row `row`; zeros outside.
    auto load_raw = [&](int row, float* v) {
        if (row >= 0 && row < IMG_H) {
            const float* rp = base + row * IMG_W;
            if (interior) {
                float4 a  = *reinterpret_cast<const float4*>(rp + c0 - 4);
                float4 bb = *reinterpret_cast<const float4*>(rp + c0);
                float4 c  = *reinterpret_cast<const float4*>(rp + c0 + 4);
                v[0]=a.x;  v[1]=a.y;  v[2]=a.z;   v[3]=a.w;
                v[4]=bb.x; v[5]=bb.y; v[6]=bb.z;  v[7]=bb.w;
                v[8]=c.x;  v[9]=c.y;  v[10]=c.z;  v[11]=c.w;
            } else {
                #pragma unroll
                for (int i = 0; i < 12; ++i) {
                    int col = c0 - 4 + i;
                    v[i] = (col >= 0 && col < IMG_W) ? rp[col] : 0.f;
                }
            }
        } else {
            #pragma unroll
            for (int i = 0; i < 12; ++i) v[i] = 0.f;
        }
    };

    // Horizontal 7-sums for the 4 output cols from 12 raw values.
    // window for output col (c0+k) = v[k+1 .. k+7]
    auto hsum = [&](const float* v, float* h, float* q) {
        float s = v[1]+v[2]+v[3]+v[4]+v[5]+v[6]+v[7];
        h[0] = s;
        s = s - v[1] + v[8];  h[1] = s;
        s = s - v[2] + v[9];  h[2] = s;
        h[3] = s - v[3] + v[10];
        float sq[11];
        #pragma unroll
        for (int i = 1; i <= 10; ++i) sq[i] = v[i] * v[i];
        float t = sq[1]+sq[2]+sq[3]+sq[4]+sq[5]+sq[6]+sq[7];
        q[0] = t;
        t = t - sq[1] + sq[8];  q[1] = t;
        t = t - sq[2] + sq[9];  q[2] = t;
        q[3] = t - sq[3] + sq[10];
    };

    // Prologue: rows y0-3 .. y0+2 -> ring slots 0..5, accumulating vh/vq.
    // Exits with b[0] = row y0+3, b[1] = row y0+4.
    load_raw(y0 - 3, b[0]);
    load_raw(y0 - 2, b[1]);
    #pragma unroll
    for (int j = 0; j < 6; ++j) {
        hsum(b[j & 1], rh[j], rq[j]);
        load_raw(y0 - 1 + j, b[j & 1]);           // j=0 -> y0-1 ... j=5 -> y0+4
        #pragma unroll
        for (int k = 0; k < 4; ++k) { vh[k] += rh[j][k]; vq[k] += rq[j][k]; }
    }
    #pragma unroll
    for (int k = 0; k < 4; ++k) { rh[6][k] = 0.f; rq[6][k] = 0.f; }

    // Main loop (full unroll: all indices/guards static). Iteration rr:
    // slot s=(6+rr)%7 holds the DEPARTING row y0+rr-4 (zeros when rr=0);
    // subtract it, overwrite with arriving row y0+rr+3 (from b[rr&1]), add,
    // emit output row y0+rr. Refill b[rr&1] one row ahead.
    #pragma unroll
    for (int rr = 0; rr < SH; ++rr) {
        const int s = (6 + rr) % 7;
        #pragma unroll
        for (int k = 0; k < 4; ++k) { vh[k] -= rh[s][k]; vq[k] -= rq[s][k]; }

        hsum(b[rr & 1], rh[s], rq[s]);
        if (rr <= 5) load_raw(y0 + rr + 5, b[rr & 1]);

        float o[4];
        #pragma unroll
        for (int k = 0; k < 4; ++k) {
            vh[k] += rh[s][k]; vq[k] += rq[s][k];
            float mean = w * vh[k];
            float var  = fmaf(w, vq[k], -(mean * mean));
            o[k] = __builtin_amdgcn_sqrtf(fmaxf(var, 0.f));
        }
        *reinterpret_cast<float4*>(obase + (size_t)(y0 + rr) * IMG_W + c0) =
            make_float4(o[0], o[1], o[2], o[3]);
    }
}

extern "C" void kernel_launch(void* const* d_in, const int* in_sizes, int n_in,
                              void* d_out, int out_size, void* d_ws, size_t ws_size,
                              hipStream_t stream) {
    const float* img = (const float*)d_in[0];
    const float* wt  = (const float*)d_in[1];
    float* out = (float*)d_out;
    const int batch = in_sizes[0] / (IMG_W * IMG_H);   // 16
    dim3 grid(1, IMG_H / SH, batch);                   // 2048 blocks
    patchstd_kernel<<<grid, dim3(TPB, 1, 1), 0, stream>>>(img, wt, out);
}

// Round 7
// 36.256 us; speedup vs baseline: 4.5252x; 4.5252x over previous
//
#include <hip/hip_runtime.h>

// PatchStd: out = sqrt( boxconv7(x^2) - boxconv7(x)^2 ), uniform 7x7 weight w.
// x: [16, 1, 1024, 1024] fp32, zero padding 3 on each side.
//
// Uniform weight => conv = w * windowed sum. Thread owns 4 adjacent output
// cols and an 8-row strip (TPB=256, 2048 blocks — R2's proven config).
// Per input row: 3 aligned float4 loads -> sliding-window horizontal 7-sums
// (x, x^2) -> 7-deep register ring. Vertical window is a RUNNING sum
// (vh += h_new - h_departing; departing row shares the ring slot being
// overwritten; slot 6 zero-init covers the first iteration): -40% VALU vs
// the full 7-row re-sum. R6 lesson: __launch_bounds__ min-waves=7 forced
// VGPR=36 and spilled the ring to scratch (WRITE 321MB, 164us). No
// occupancy floor here — let the allocator keep the ring resident (~70 VGPR
// -> 7 waves/SIMD naturally).

#define IMG_W 1024
#define IMG_H 1024
#define SH    8             // output rows per block strip
#define TPB   256           // threads/block; 4 cols/thread -> 1024 cols

__global__ __launch_bounds__(TPB) void patchstd_kernel(
    const float* __restrict__ img, const float* __restrict__ wptr,
    float* __restrict__ out)
{
    const int tx = threadIdx.x;
    const int c0 = tx << 2;                       // first of 4 output cols
    const int y0 = blockIdx.y * SH;               // first output row of strip
    const float* base  = img + (size_t)blockIdx.z * (IMG_W * IMG_H);
    float*       obase = out + (size_t)blockIdx.z * (IMG_W * IMG_H);
    const float w = wptr[0];

    const bool interior = (tx > 0) && (tx < 255); // all 12 cols in-range

    float rh[7][4];     // ring: horizontal 7-sums of x   (per row)
    float rq[7][4];     // ring: horizontal 7-sums of x^2 (per row)
    float vh[4] = {0.f, 0.f, 0.f, 0.f};           // running vertical sums
    float vq[4] = {0.f, 0.f, 0.f, 0.f};
    float b[2][12];                               // alternating raw-row buffers

    // Load 12 raw pixels (cols c0-4 .. c0+7) of input row `row`; zeros outside.
    auto load_raw = [&](int row, float* v) {
        if (row >= 0 && row < IMG_H) {
            const float* rp = base + row * IMG_W;
            if (interior) {
                float4 a  = *reinterpret_cast<const float4*>(rp + c0 - 4);
                float4 bb = *reinterpret_cast<const float4*>(rp + c0);
                float4 c  = *reinterpret_cast<const float4*>(rp + c0 + 4);
                v[0]=a.x;  v[1]=a.y;  v[2]=a.z;   v[3]=a.w;
                v[4]=bb.x; v[5]=bb.y; v[6]=bb.z;  v[7]=bb.w;
                v[8]=c.x;  v[9]=c.y;  v[10]=c.z;  v[11]=c.w;
            } else {
                #pragma unroll
                for (int i = 0; i < 12; ++i) {
                    int col = c0 - 4 + i;
                    v[i] = (col >= 0 && col < IMG_W) ? rp[col] : 0.f;
                }
            }
        } else {
            #pragma unroll
            for (int i = 0; i < 12; ++i) v[i] = 0.f;
        }
    };

    // Horizontal 7-sums for the 4 output cols from 12 raw values.
    // window for output col (c0+k) = v[k+1 .. k+7]
    auto hsum = [&](const float* v, float* h, float* q) {
        float s = v[1]+v[2]+v[3]+v[4]+v[5]+v[6]+v[7];
        h[0] = s;
        s = s - v[1] + v[8];  h[1] = s;
        s = s - v[2] + v[9];  h[2] = s;
        h[3] = s - v[3] + v[10];
        float sq[11];
        #pragma unroll
        for (int i = 1; i <= 10; ++i) sq[i] = v[i] * v[i];
        float t = sq[1]+sq[2]+sq[3]+sq[4]+sq[5]+sq[6]+sq[7];
        q[0] = t;
        t = t - sq[1] + sq[8];  q[1] = t;
        t = t - sq[2] + sq[9];  q[2] = t;
        q[3] = t - sq[3] + sq[10];
    };

    // Prologue: rows y0-3 .. y0+2 -> ring slots 0..5, accumulating vh/vq.
    // Exits with b[0] = row y0+3, b[1] = row y0+4.
    load_raw(y0 - 3, b[0]);
    load_raw(y0 - 2, b[1]);
    #pragma unroll
    for (int j = 0; j < 6; ++j) {
        hsum(b[j & 1], rh[j], rq[j]);
        load_raw(y0 - 1 + j, b[j & 1]);           // j=0 -> y0-1 ... j=5 -> y0+4
        #pragma unroll
        for (int k = 0; k < 4; ++k) { vh[k] += rh[j][k]; vq[k] += rq[j][k]; }
    }
    #pragma unroll
    for (int k = 0; k < 4; ++k) { rh[6][k] = 0.f; rq[6][k] = 0.f; }

    // Main loop (full unroll: all indices/guards static). Iteration rr:
    // slot s=(6+rr)%7 holds the DEPARTING row y0+rr-4 (zeros when rr=0);
    // subtract it, overwrite with arriving row y0+rr+3 (from b[rr&1]), add,
    // emit output row y0+rr. Refill b[rr&1] one row ahead.
    #pragma unroll
    for (int rr = 0; rr < SH; ++rr) {
        const int s = (6 + rr) % 7;
        #pragma unroll
        for (int k = 0; k < 4; ++k) { vh[k] -= rh[s][k]; vq[k] -= rq[s][k]; }

        hsum(b[rr & 1], rh[s], rq[s]);
        if (rr <= 5) load_raw(y0 + rr + 5, b[rr & 1]);

        float o[4];
        #pragma unroll
        for (int k = 0; k < 4; ++k) {
            vh[k] += rh[s][k]; vq[k] += rq[s][k];
            float mean = w * vh[k];
            float var  = fmaf(w, vq[k], -(mean * mean));
            o[k] = __builtin_amdgcn_sqrtf(fmaxf(var, 0.f));
        }
        *reinterpret_cast<float4*>(obase + (size_t)(y0 + rr) * IMG_W + c0) =
            make_float4(o[0], o[1], o[2], o[3]);
    }
}

extern "C" void kernel_launch(void* const* d_in, const int* in_sizes, int n_in,
                              void* d_out, int out_size, void* d_ws, size_t ws_size,
                              hipStream_t stream) {
    const float* img = (const float*)d_in[0];
    const float* wt  = (const float*)d_in[1];
    float* out = (float*)d_out;
    const int batch = in_sizes[0] / (IMG_W * IMG_H);   // 16
    dim3 grid(1, IMG_H / SH, batch);                   // 2048 blocks
    patchstd_kernel<<<grid, dim3(TPB, 1, 1), 0, stream>>>(img, wt, out);
}

// Round 8
// 32.654 us; speedup vs baseline: 5.0244x; 1.1103x over previous
//
#include <hip/hip_runtime.h>

// PatchStd: out = sqrt( boxconv7(x^2) - boxconv7(x)^2 ), uniform 7x7 weight w.
// x: [16, 1, 1024, 1024] fp32, zero padding 3 on each side.
//
// R7 diagnosis: latency-bound (VALU 23%, HBM 32%, ~1 load in flight/wave).
// Fix: wave-private LDS row-ring filled by global_load_lds DMA issued 3 rows
// ahead, consumed under exact counted s_waitcnt vmcnt(N) (never 0 mid-loop).
// Per row per wave: 2 DMA ops (dwordx4 covering 256 floats + dword tail of
// 16) staging the wave's 272-float halo segment; threads then ds_read their
// 12-float windows (3x b128), sliding-window horizontal 7-sums, 7-deep h/q
// ring with vertical running sums (R7's VALU structure, unchanged & proven).
// No barriers: each wave reads only its own segment. Row/col boundaries:
// clamped addresses + zero-patch at consume (2 edge lanes, OOB rows).
// LDS 4 waves * 4 slots * 320 floats = 20 KB/block.

#define IMG_W 1024
#define IMG_H 1024
#define SH    8             // output rows per block strip
#define TPB   256
#define NR    (SH + 6)      // 14 input rows per strip
#define RING  4
#define SEGF  320           // floats per LDS slot (272 used, padded)

typedef float v4f __attribute__((ext_vector_type(4)));

#define WAITV(N) asm volatile("s_waitcnt vmcnt(" #N ")" ::: "memory")

__global__ __launch_bounds__(TPB) void patchstd_kernel(
    const float* __restrict__ img, const float* __restrict__ wptr,
    float* __restrict__ out)
{
    __shared__ float lds[4 * RING * SEGF];          // 20 KB

    const int tx   = threadIdx.x;
    const int w_   = tx >> 6;                       // wave id 0..3 (uniform)
    const int lane = tx & 63;
    const int c0   = tx << 2;                       // first of 4 output cols
    const int y0   = blockIdx.y * SH;
    const float* base  = img + (size_t)blockIdx.z * (IMG_W * IMG_H);
    float*       obase = out + (size_t)blockIdx.z * (IMG_W * IMG_H);
    const float w = wptr[0];

    // Wave w_ covers output cols [256w, 256w+256); segment = cols Sw..Sw+271
    // (Sw = 256w-8), so thread's 12-float window (c0-4..c0+7) sits at segment
    // float index 4*lane+4. Per-lane global col offsets, clamped in-row
    // (clamped lanes produce garbage that is either unconsumed or zero-patched).
    const int Sw   = 256 * w_ - 8;
    const int colA = min(max(Sw + 4 * lane, 0), IMG_W - 4);   // dwordx4 quad
    const int colB = min(max(Sw + 256 + lane, 0), IMG_W - 1); // dword tail
    const float* gA = base + colA;
    const float* gB = base + colB;
    float* const seg0 = &lds[w_ * (RING * SEGF)];

    // Issue row j's segment DMA into ring slot j&3 (wave-uniform LDS base).
    auto issue = [&](int j) {
        const int rc = min(max(y0 - 3 + j, 0), IMG_H - 1);    // clamped row
        const size_t ro = (size_t)rc * IMG_W;
        float* sl = seg0 + (j & (RING - 1)) * SEGF;
        __builtin_amdgcn_global_load_lds(
            (const __attribute__((address_space(1))) void*)(gA + ro),
            (__attribute__((address_space(3))) void*)sl, 16, 0, 0);
        __builtin_amdgcn_global_load_lds(
            (const __attribute__((address_space(1))) void*)(gB + ro),
            (__attribute__((address_space(3))) void*)(sl + 256), 4, 0, 0);
    };

    // Horizontal 7-sums for 4 output cols from 12 raw values
    // (window for col c0+k = v[k+1..k+7]).
    auto hsum = [&](const float* v, float* h, float* q) {
        float s = v[1]+v[2]+v[3]+v[4]+v[5]+v[6]+v[7];
        h[0] = s;
        s = s - v[1] + v[8];  h[1] = s;
        s = s - v[2] + v[9];  h[2] = s;
        h[3] = s - v[3] + v[10];
        float sq[11];
        #pragma unroll
        for (int i = 1; i <= 10; ++i) sq[i] = v[i] * v[i];
        float t = sq[1]+sq[2]+sq[3]+sq[4]+sq[5]+sq[6]+sq[7];
        q[0] = t;
        t = t - sq[1] + sq[8];  q[1] = t;
        t = t - sq[2] + sq[9];  q[2] = t;
        q[3] = t - sq[3] + sq[10];
    };

    float rh[7][4], rq[7][4];                       // h/q ring (7 rows)
    float vh[4] = {0.f,0.f,0.f,0.f};                // vertical running sums
    float vq[4] = {0.f,0.f,0.f,0.f};

    issue(0); issue(1); issue(2);                   // 3-deep pipeline fill

    // Full unroll: ring slots, vmcnt immediates, guards all compile-time.
    // vmcnt(N) = exact count of vm-ops younger than row j's 2 loads, in
    // issue order: 2 loads per issued row, 1 store per emitted output.
    #pragma unroll
    for (int j = 0; j < NR; ++j) {
        if (j + 3 < NR) issue(j + 3);

        if      (j <= 6)  WAITV(6);
        else if (j == 7)  WAITV(7);
        else if (j == 8)  WAITV(8);
        else if (j == 9)  WAITV(9);
        else if (j == 10) WAITV(9);
        else if (j == 11) WAITV(7);
        else if (j == 12) WAITV(5);
        else              WAITV(3);

        // Consume row j from LDS: 3x ds_read_b128.
        const float* seg = seg0 + (j & (RING - 1)) * SEGF;
        const v4f* p = (const v4f*)(seg + 4 * lane + 4);
        v4f A = p[0], B = p[1], C = p[2];
        float v[12] = {A.x,A.y,A.z,A.w, B.x,B.y,B.z,B.w, C.x,C.y,C.z,C.w};
        if (tx == 0)   { v[0]=0.f; v[1]=0.f; v[2]=0.f;  v[3]=0.f;  }
        if (tx == 255) { v[8]=0.f; v[9]=0.f; v[10]=0.f; v[11]=0.f; }

        float h[4], q[4];
        const int R = y0 - 3 + j;
        if (R < 0 || R >= IMG_H) {                  // block-uniform branch
            #pragma unroll
            for (int k = 0; k < 4; ++k) { h[k] = 0.f; q[k] = 0.f; }
        } else {
            hsum(v, h, q);
        }

        if (j < 6) {                                // warm the vertical window
            #pragma unroll
            for (int k = 0; k < 4; ++k) {
                rh[j][k] = h[k]; rq[j][k] = q[k];
                vh[k] += h[k];   vq[k] += q[k];
            }
            if (j == 5) {
                #pragma unroll
                for (int k = 0; k < 4; ++k) { rh[6][k] = 0.f; rq[6][k] = 0.f; }
            }
        } else {                                    // steady state: emit a row
            const int s = j % 7;                    // departing row's slot
            float o[4];
            #pragma unroll
            for (int k = 0; k < 4; ++k) {
                vh[k] += h[k] - rh[s][k];
                vq[k] += q[k] - rq[s][k];
                rh[s][k] = h[k]; rq[s][k] = q[k];
                float mean = w * vh[k];
                float var  = fmaf(w, vq[k], -(mean * mean));
                o[k] = __builtin_amdgcn_sqrtf(fmaxf(var, 0.f));
            }
            *reinterpret_cast<float4*>(obase + (size_t)(y0 + j - 6) * IMG_W + c0) =
                make_float4(o[0], o[1], o[2], o[3]);
        }
    }
}

extern "C" void kernel_launch(void* const* d_in, const int* in_sizes, int n_in,
                              void* d_out, int out_size, void* d_ws, size_t ws_size,
                              hipStream_t stream) {
    const float* img = (const float*)d_in[0];
    const float* wt  = (const float*)d_in[1];
    float* out = (float*)d_out;
    const int batch = in_sizes[0] / (IMG_W * IMG_H);   // 16
    dim3 grid(1, IMG_H / SH, batch);                   // 2048 blocks
    patchstd_kernel<<<grid, dim3(TPB, 1, 1), 0, stream>>>(img, wt, out);
}